// Round 4
// baseline (355.025 us; speedup 1.0000x reference)
//
#include <hip/hip_runtime.h>

typedef unsigned short u16;
typedef unsigned int u32;
typedef __bf16 bf16x8 __attribute__((ext_vector_type(8)));
typedef float f32x4 __attribute__((ext_vector_type(4)));
typedef u16 ushortx8 __attribute__((ext_vector_type(8)));

__device__ __forceinline__ u16 f2bf(float f) {
  u32 u = __float_as_uint(f);
  u32 r = (u + 0x7FFFu + ((u >> 16) & 1u)) >> 16;
  return (u16)r;
}
__device__ __forceinline__ float bf2f(u16 v) {
  return __uint_as_float((u32)v << 16);
}

__device__ __forceinline__ float gelu_exact(float x) {
  return 0.5f * x * (1.f + erff(x * 0.70710678118654752f));
}

// async global->LDS, 16B per lane. LDS dest is wave-uniform base + lane*16.
__device__ __forceinline__ void gload16(const u16* g, u16* l) {
  __builtin_amdgcn_global_load_lds((const __attribute__((address_space(1))) void*)g,
                                   (__attribute__((address_space(3))) void*)l, 16, 0, 0);
}

// ---------------- transpose + cast fp32 [R,C] -> bf16 [C,R] ----------------
__global__ void transpose_cast(const float* __restrict__ in, u16* __restrict__ out,
                               int R, int C) {
  __shared__ float tile[32][33];
  int c0 = blockIdx.x * 32, r0 = blockIdx.y * 32;
  int tx = threadIdx.x, ty = threadIdx.y;  // 32 x 8
  for (int i = 0; i < 32; i += 8) {
    int r = r0 + ty + i, c = c0 + tx;
    tile[ty + i][tx] = (r < R && c < C) ? in[(long)r * C + c] : 0.f;
  }
  __syncthreads();
  for (int i = 0; i < 32; i += 8) {
    int oc = c0 + ty + i, orr = r0 + tx;
    if (oc < C && orr < R) out[(long)oc * R + orr] = f2bf(tile[tx][ty + i]);
  }
}

// ------- W_eff^T[n,d] = sum_j lin_w[j*64+d, n]  (tile-of-12 folded GEMM) -------
__global__ void weff_build(const float* __restrict__ lin_w, u16* __restrict__ weffT) {
  int idx = blockIdx.x * 256 + threadIdx.x;
  if (idx >= 768 * 64) return;
  int n = idx % 768, d = idx / 768;
  float s = 0.f;
#pragma unroll
  for (int j = 0; j < 12; j++) s += lin_w[(long)(j * 64 + d) * 768 + n];
  weffT[(long)n * 64 + d] = f2bf(s);
}

// ---------------- LayerNorm: one wave per 768-row, bf16 out ----------------
__global__ __launch_bounds__(256)
void ln_rows(const float* __restrict__ in, const float* __restrict__ gamma,
             const float* __restrict__ beta, u16* __restrict__ out, int nrows) {
  int gid = blockIdx.x * blockDim.x + threadIdx.x;
  int wid = gid >> 6, l = gid & 63;
  if (wid >= nrows) return;
  const float4* row = (const float4*)(in + (long)wid * 768);
  float4 v[3];
  float s = 0.f, s2 = 0.f;
#pragma unroll
  for (int j = 0; j < 3; j++) {
    v[j] = row[l + 64 * j];
    s += v[j].x + v[j].y + v[j].z + v[j].w;
    s2 += v[j].x * v[j].x + v[j].y * v[j].y + v[j].z * v[j].z + v[j].w * v[j].w;
  }
#pragma unroll
  for (int off = 1; off < 64; off <<= 1) {
    s += __shfl_xor(s, off);
    s2 += __shfl_xor(s2, off);
  }
  float mean = s * (1.f / 768.f);
  float rstd = rsqrtf(s2 * (1.f / 768.f) - mean * mean + 1e-5f);
  u16* orow = out + (long)wid * 768;
#pragma unroll
  for (int j = 0; j < 3; j++) {
    float4 g = ((const float4*)gamma)[l + 64 * j];
    float4 b = ((const float4*)beta)[l + 64 * j];
    ushort4 o;
    o.x = f2bf((v[j].x - mean) * rstd * g.x + b.x);
    o.y = f2bf((v[j].y - mean) * rstd * g.y + b.y);
    o.z = f2bf((v[j].z - mean) * rstd * g.z + b.z);
    o.w = f2bf((v[j].w - mean) * rstd * g.w + b.w);
    ((ushort4*)orow)[l + 64 * j] = o;
  }
}

// ------------- generic bf16 GEMM (128x128, BK=32, m97-style) for small GEMMs -------------
// EPI 0: bf16 out, no bias.  EPI 1: f32 out = acc + bias + res.
template <int EPI>
__global__ __launch_bounds__(256, 2)
void gemm_bt(const u16* __restrict__ A, const u16* __restrict__ Bt,
             const float* __restrict__ bias, const float* __restrict__ res,
             void* __restrict__ outv, int M, int N, int K, int ldo) {
  __shared__ __align__(16) u16 Alds[128 * 32];
  __shared__ __align__(16) u16 Blds[128 * 32];
  const int t = threadIdx.x;
  const int w = t >> 6, l = t & 63;
  const int wr = w >> 1, wc = w & 1;
  const int srow = w * 32 + (l >> 2);
  const int scol = (l & 3) * 8;
  const u16* aptr = A + (long)(blockIdx.x * 128 + srow) * K + scol;
  const u16* bptr = Bt + (long)(blockIdx.y * 128 + srow) * K + scol;
  const long j16 = (long)16 * K;
  u16* albase = &Alds[(w * 32) * 32];
  u16* blbase = &Blds[(w * 32) * 32];
  const int ar = (wr * 64 + (l & 15)) * 32 + (l >> 4) * 8;
  const int br = (wc * 64 + (l & 15)) * 32 + (l >> 4) * 8;
  f32x4 acc[4][4] = {};
  for (int ks = 0; ks < K; ks += 32) {
    __syncthreads();
    gload16(aptr, albase);
    gload16(aptr + j16, albase + 16 * 32);
    gload16(bptr, blbase);
    gload16(bptr + j16, blbase + 16 * 32);
    asm volatile("s_waitcnt vmcnt(0)" ::: "memory");
    __syncthreads();
    bf16x8 af[4], bfr[4];
#pragma unroll
    for (int i = 0; i < 4; i++) af[i] = *(const bf16x8*)(&Alds[ar + i * 16 * 32]);
#pragma unroll
    for (int i = 0; i < 4; i++) bfr[i] = *(const bf16x8*)(&Blds[br + i * 16 * 32]);
#pragma unroll
    for (int mf = 0; mf < 4; mf++)
#pragma unroll
      for (int nf = 0; nf < 4; nf++)
        acc[mf][nf] = __builtin_amdgcn_mfma_f32_16x16x32_bf16(af[mf], bfr[nf], acc[mf][nf], 0, 0, 0);
    aptr += 32;
    bptr += 32;
  }
  const int rowbase = blockIdx.x * 128 + wr * 64 + ((l >> 4) * 4);
  const int colbase = blockIdx.y * 128 + wc * 64 + (l & 15);
#pragma unroll
  for (int nf = 0; nf < 4; nf++) {
    int col = colbase + nf * 16;
    if (col >= N) continue;
    float bv = (EPI == 0) ? 0.f : bias[col];
#pragma unroll
    for (int mf = 0; mf < 4; mf++) {
#pragma unroll
      for (int i = 0; i < 4; i++) {
        long row = rowbase + mf * 16 + i;
        float v = acc[mf][nf][i] + bv;
        if (EPI == 1) {
          v += res[row * ldo + col];
          ((float*)outv)[row * ldo + col] = v;
        } else {
          ((u16*)outv)[row * ldo + col] = f2bf(v);
        }
      }
    }
  }
}

// ================= 256x256 8-phase GEMM (m201 template, race-fixed) =================
// BK=64, 2-dbuf 128KiB LDS, 8 waves (2Mx4N), wave tile 128x64.
// Half-tile stage order per K-tile: h0=B-half0, h1=A-half0, h2=A-half1, h3=B-half1.
// Stage lead 6: tile T's phases stage {T+1h2, T+1h3, T+2h0, T+2h1}.
//   Current-buffer stages: B-half at P3 (B consumed end-P2), A-half at P4 (A consumed end-P3).
// Reads: A @ {P1,P3}, B @ {P1,P2}. Boundary waits: vmcnt(4) steady, vmcnt(0) into last tile.
// EPI 2: bf16 gelu(acc+bias).  EPI 4: bf16 raw partial at outv + z*M*ldo.
template <int EPI>
__global__ __launch_bounds__(512, 2)
void gemm8p(const u16* __restrict__ A, const u16* __restrict__ Bt,
            const float* __restrict__ bias, u16* __restrict__ outv,
            int M, int N, int lda, int Ks, int ldo) {
  __shared__ __align__(16) u16 lds[2][2][16384];  // [dbuf][A=0/B=1][half*8192 + r*64 + c]
  const int t = threadIdx.x;
  const int w = t >> 6, l = t & 63;
  const int wm = w >> 2, wn = w & 3;
  const int NT = Ks >> 6;
  const long kb = (long)blockIdx.z * Ks;
  const u16* Ag = A + (long)blockIdx.x * 256 * lda + kb;
  const u16* Bg = Bt + (long)blockIdx.y * 256 * lda + kb;
  // staging: chunk c (16B) sits at linear LDS chunk c = row*8 + slot; holds logical
  // k-chunk = slot ^ (row&7). Inverse-swizzled global source per lane (rule #21).
  const int c0 = t, c1 = t + 512;
  const int r0 = c0 >> 3, r1 = c1 >> 3;
  const int co0 = ((c0 & 7) ^ (r0 & 7)) << 3;
  const int co1 = ((c1 & 7) ^ (r1 & 7)) << 3;
  const int db0 = w * 512;         // u16 offset of wave's chunk base, issue 0
  const int db1 = 4096 + w * 512;  // issue 1
  // swizzled ds_read offsets: slot = (l>>4 [+4 for ks=1]) ^ (row&7), row&7 == l&7
  const int arb = (wm * 128 + (l & 15)) * 64;
  const int brb = (wn * 64 + (l & 15)) * 64;
  const int ck0 = (((l >> 4) + 0) ^ (l & 7)) << 3;
  const int ck1 = (((l >> 4) + 4) ^ (l & 7)) << 3;

  f32x4 acc[8][4] = {};
  bf16x8 a[4][2], b0[2][2], b1[2][2];

  auto STAGE = [&](int s) {
    if (s >= 4 * NT) return;
    int T = s >> 2, h = s & 3;
    int isB = (h == 0 || h == 3);    // h0,h3 = B halves; h1,h2 = A halves
    int half = h >> 1;               // h0->B0, h1->A0, h2->A1, h3->B1
    u16* base = &lds[T & 1][isB][half * 8192];
    const u16* src = (isB ? Bg : Ag) + (long)(half * 128) * lda + T * 64;
    gload16(src + (long)r0 * lda + co0, base + db0);
    gload16(src + (long)r1 * lda + co1, base + db1);
  };
  auto LDA_ = [&](int buf, int qm) {
#pragma unroll
    for (int i = 0; i < 4; i++) {
      const u16* base = &lds[buf][0][arb + (qm * 4 + i) * 1024];
      a[i][0] = *(const bf16x8*)(base + ck0);
      a[i][1] = *(const bf16x8*)(base + ck1);
    }
  };
  auto LDB_ = [&](int buf, int qn, bf16x8 (&bb)[2][2]) {
#pragma unroll
    for (int j = 0; j < 2; j++) {
      const u16* base = &lds[buf][1][brb + (qn * 2 + j) * 1024];
      bb[j][0] = *(const bf16x8*)(base + ck0);
      bb[j][1] = *(const bf16x8*)(base + ck1);
    }
  };
  auto MM = [&](int qm, int qn, bf16x8 (&bb)[2][2]) {
    __builtin_amdgcn_s_setprio(1);
#pragma unroll
    for (int i = 0; i < 4; i++)
#pragma unroll
      for (int j = 0; j < 2; j++)
#pragma unroll
        for (int ks = 0; ks < 2; ks++)
          acc[qm * 4 + i][qn * 2 + j] = __builtin_amdgcn_mfma_f32_16x16x32_bf16(
              a[i][ks], bb[j][ks], acc[qm * 4 + i][qn * 2 + j], 0, 0, 0);
    __builtin_amdgcn_s_setprio(0);
  };
  auto SB = [&]() {
    __builtin_amdgcn_s_barrier();
    __builtin_amdgcn_sched_barrier(0);  // pin phase contents (rule #18/#19 guard)
  };

  // prologue: T0 fully (h0..h3) + T1 h0,h1 in flight = 12 loads
  for (int i = 0; i < 6; i++) STAGE(i);
  asm volatile("s_waitcnt vmcnt(4)" ::: "memory");  // T0's 8 landed
  SB();
  for (int T = 0; T < NT; T++) {
    const int buf = T & 1;
    // P1
    LDA_(buf, 0); LDB_(buf, 0, b0); STAGE(4 * T + 6);
    SB(); MM(0, 0, b0); SB();
    // P2
    LDB_(buf, 1, b1); STAGE(4 * T + 7);
    SB(); MM(0, 1, b1); SB();
    // P3
    LDA_(buf, 1); STAGE(4 * T + 8);
    SB(); MM(1, 1, b1); SB();
    // P4 + tile boundary wait
    STAGE(4 * T + 9);
    if (T < NT - 2) { asm volatile("s_waitcnt vmcnt(4)" ::: "memory"); }
    else            { asm volatile("s_waitcnt vmcnt(0)" ::: "memory"); }
    SB(); MM(1, 0, b0); SB();
  }

  const int rowb = blockIdx.x * 256 + wm * 128 + ((l >> 4) * 4);
  const int colb = blockIdx.y * 256 + wn * 64 + (l & 15);
  u16* op = outv + (EPI == 4 ? (size_t)blockIdx.z * M * ldo : (size_t)0);
#pragma unroll
  for (int nf = 0; nf < 4; nf++) {
    int col = colb + nf * 16;
    float bv = (EPI == 2) ? bias[col] : 0.f;
#pragma unroll
    for (int mf = 0; mf < 8; mf++) {
#pragma unroll
      for (int i = 0; i < 4; i++) {
        long row = rowb + mf * 16 + i;
        float v = acc[mf][nf][i] + bv;
        if (EPI == 2) v = gelu_exact(v);
        op[row * ldo + col] = f2bf(v);
      }
    }
  }
}

// out = p0 + p1 + bias + res  (FC2 split-K reduce, f32 out)
__global__ __launch_bounds__(256)
void fc2_reduce(const u16* __restrict__ p, const float* __restrict__ bias,
                const float* __restrict__ res, float* __restrict__ out) {
  size_t base = ((size_t)blockIdx.x * 256 + threadIdx.x) * 8;
  ushortx8 pa = *(const ushortx8*)(p + base);
  ushortx8 pb = *(const ushortx8*)(p + (size_t)8192 * 768 + base);
  int col = (int)(base % 768);
  float4 r0 = *(const float4*)(res + base);
  float4 r1 = *(const float4*)(res + base + 4);
  float4 g0 = *(const float4*)(bias + col);
  float4 g1 = *(const float4*)(bias + col + 4);
  float4 o0, o1;
  o0.x = bf2f(pa[0]) + bf2f(pb[0]) + r0.x + g0.x;
  o0.y = bf2f(pa[1]) + bf2f(pb[1]) + r0.y + g0.y;
  o0.z = bf2f(pa[2]) + bf2f(pb[2]) + r0.z + g0.z;
  o0.w = bf2f(pa[3]) + bf2f(pb[3]) + r0.w + g0.w;
  o1.x = bf2f(pa[4]) + bf2f(pb[4]) + r1.x + g1.x;
  o1.y = bf2f(pa[5]) + bf2f(pb[5]) + r1.y + g1.y;
  o1.z = bf2f(pa[6]) + bf2f(pb[6]) + r1.z + g1.z;
  o1.w = bf2f(pa[7]) + bf2f(pb[7]) + r1.w + g1.w;
  *(float4*)(out + base) = o0;
  *(float4*)(out + base + 4) = o1;
}

// ---------------- flash attention, 4-way KV split ----------------
__global__ __launch_bounds__(128)
void attn_fwd(const u16* __restrict__ qkv, float* __restrict__ pout,
              float* __restrict__ pm, float* __restrict__ pl) {
  __shared__ __align__(16) u16 Klds[32 * 72];
  __shared__ __align__(16) u16 Vlds[64 * 40];
  __shared__ __align__(16) u16 Plds[2][16 * 40];
  const int t = threadIdx.x, w = t >> 6, l = t & 63;
  const int r0 = blockIdx.x * 32;
  const int sp = blockIdx.y;
  const long bb = (long)(r0 & ~2047);
  const int qrow = r0 + w * 16 + (l & 15);
  bf16x8 qf0 = *(const bf16x8*)(qkv + (long)qrow * 192 + ((l >> 4) * 8));
  bf16x8 qf1 = *(const bf16x8*)(qkv + (long)qrow * 192 + 32 + ((l >> 4) * 8));
  f32x4 po[4] = {};
  float m_i[4], l_i[4];
#pragma unroll
  for (int i = 0; i < 4; i++) { m_i[i] = -1e30f; l_i[i] = 0.f; }
  const int kkey = t >> 3, kseg = t & 7;
  for (int st = sp * 512; st < sp * 512 + 512; st += 32) {
    uint4 k0 = *(const uint4*)(qkv + (bb + st + kkey) * 192 + 64 + kseg * 8);
    uint4 k1 = *(const uint4*)(qkv + (bb + st + 16 + kkey) * 192 + 64 + kseg * 8);
    u16 vv[16];
#pragma unroll
    for (int i = 0; i < 16; i++) {
      int e = t + 128 * i;
      vv[i] = qkv[(bb + st + (e >> 6)) * 192 + 128 + (e & 63)];
    }
    __syncthreads();
    *(uint4*)(&Klds[kkey * 72 + kseg * 8]) = k0;
    *(uint4*)(&Klds[(16 + kkey) * 72 + kseg * 8]) = k1;
#pragma unroll
    for (int i = 0; i < 16; i++) {
      int e = t + 128 * i;
      Vlds[(e & 63) * 40 + (e >> 6)] = vv[i];
    }
    __syncthreads();
    f32x4 s0 = {}, s1 = {};
    {
      bf16x8 ka = *(const bf16x8*)(&Klds[(l & 15) * 72 + ((l >> 4) * 8)]);
      bf16x8 kb = *(const bf16x8*)(&Klds[(l & 15) * 72 + 32 + ((l >> 4) * 8)]);
      s0 = __builtin_amdgcn_mfma_f32_16x16x32_bf16(qf0, ka, s0, 0, 0, 0);
      s0 = __builtin_amdgcn_mfma_f32_16x16x32_bf16(qf1, kb, s0, 0, 0, 0);
      bf16x8 kc = *(const bf16x8*)(&Klds[(16 + (l & 15)) * 72 + ((l >> 4) * 8)]);
      bf16x8 kd = *(const bf16x8*)(&Klds[(16 + (l & 15)) * 72 + 32 + ((l >> 4) * 8)]);
      s1 = __builtin_amdgcn_mfma_f32_16x16x32_bf16(qf0, kc, s1, 0, 0, 0);
      s1 = __builtin_amdgcn_mfma_f32_16x16x32_bf16(qf1, kd, s1, 0, 0, 0);
    }
    float sf[4];
#pragma unroll
    for (int i = 0; i < 4; i++) {
      float a = s0[i] * 0.125f, b = s1[i] * 0.125f;
      float tm = fmaxf(a, b);
#pragma unroll
      for (int off = 1; off < 16; off <<= 1) tm = fmaxf(tm, __shfl_xor(tm, off));
      float mn = fmaxf(m_i[i], tm);
      sf[i] = __expf(m_i[i] - mn);
      m_i[i] = mn;
      a = __expf(a - mn);
      b = __expf(b - mn);
      float rs = a + b;
#pragma unroll
      for (int off = 1; off < 16; off <<= 1) rs += __shfl_xor(rs, off);
      l_i[i] = l_i[i] * sf[i] + rs;
      int prow = (l >> 4) * 4 + i;
      Plds[w][prow * 40 + (l & 15)] = f2bf(a);
      Plds[w][prow * 40 + 16 + (l & 15)] = f2bf(b);
    }
#pragma unroll
    for (int n = 0; n < 4; n++)
#pragma unroll
      for (int i = 0; i < 4; i++) po[n][i] *= sf[i];
    bf16x8 pf = *(const bf16x8*)(&Plds[w][(l & 15) * 40 + ((l >> 4) * 8)]);
#pragma unroll
    for (int n = 0; n < 4; n++) {
      bf16x8 vf = *(const bf16x8*)(&Vlds[(n * 16 + (l & 15)) * 40 + ((l >> 4) * 8)]);
      po[n] = __builtin_amdgcn_mfma_f32_16x16x32_bf16(pf, vf, po[n], 0, 0, 0);
    }
  }
#pragma unroll
  for (int i = 0; i < 4; i++) {
    long row = r0 + w * 16 + ((l >> 4) * 4) + i;
    if ((l & 15) == 0) {
      pm[(long)sp * 8192 + row] = m_i[i];
      pl[(long)sp * 8192 + row] = l_i[i];
    }
#pragma unroll
    for (int n = 0; n < 4; n++)
      pout[((long)sp * 8192 + row) * 64 + n * 16 + (l & 15)] = po[n][i];
  }
}

__global__ __launch_bounds__(256)
void attn_merge(const float* __restrict__ pout, const float* __restrict__ pm,
                const float* __restrict__ pl, u16* __restrict__ oh) {
  int gid = blockIdx.x * 256 + threadIdx.x;
  int row = gid >> 6;
  float M = -1e30f;
#pragma unroll
  for (int s = 0; s < 4; s++) M = fmaxf(M, pm[s * 8192 + row]);
  float L = 0.f, acc = 0.f;
#pragma unroll
  for (int s = 0; s < 4; s++) {
    float e = __expf(pm[s * 8192 + row] - M);
    L += pl[s * 8192 + row] * e;
    acc += pout[((long)s * 8192 + row) * 64 + (gid & 63)] * e;
  }
  oh[gid] = f2bf(acc / L);
}

extern "C" void kernel_launch(void* const* d_in, const int* in_sizes, int n_in,
                              void* d_out, int out_size, void* d_ws, size_t ws_size,
                              hipStream_t stream) {
  const float* x = (const float*)d_in[0];
  const float* wq = (const float*)d_in[1];
  const float* wk = (const float*)d_in[2];
  const float* wv = (const float*)d_in[3];
  const float* lin_w = (const float*)d_in[4];
  const float* lin_b = (const float*)d_in[5];
  const float* ln1_g = (const float*)d_in[6];
  const float* ln1_b = (const float*)d_in[7];
  const float* fc1_w = (const float*)d_in[8];
  const float* fc1_b = (const float*)d_in[9];
  const float* fc2_w = (const float*)d_in[10];
  const float* fc2_b = (const float*)d_in[11];
  float* out = (float*)d_out;

  char* p = (char*)d_ws;
  u16* wqkvT = (u16*)p; p += 256 * 768 * 2;
  u16* weffT = (u16*)p; p += 768 * 64 * 2;
  u16* fc1wT = (u16*)p; p += (size_t)3072 * 768 * 2;
  u16* fc2wT = (u16*)p; p += (size_t)768 * 3072 * 2;
  u16* h = (u16*)p; p += (size_t)8192 * 768 * 2;
  u16* qkv = (u16*)p; p += (size_t)8192 * 192 * 2;
  u16* oh = (u16*)p; p += (size_t)8192 * 64 * 2;
  float* out1 = (float*)p; p += (size_t)8192 * 768 * 4;
  u16* a1 = (u16*)p; p += (size_t)8192 * 3072 * 2;
  u16* fc2p = (u16*)p; p += (size_t)2 * 8192 * 768 * 2;  // FC2 split-K bf16 partials
  // attention partials alias a1 (a1 written only later, by FC1)
  float* pout = (float*)a1;
  float* pm = pout + (size_t)4 * 8192 * 64;
  float* pl = pm + 4 * 8192;

  dim3 tb(32, 8);
  transpose_cast<<<dim3(2, 24), tb, 0, stream>>>(wq, wqkvT, 768, 64);
  transpose_cast<<<dim3(2, 24), tb, 0, stream>>>(wk, wqkvT + 64 * 768, 768, 64);
  transpose_cast<<<dim3(2, 24), tb, 0, stream>>>(wv, wqkvT + 128 * 768, 768, 64);
  hipMemsetAsync(wqkvT + 192 * 768, 0, 64 * 768 * 2, stream);
  transpose_cast<<<dim3(96, 24), tb, 0, stream>>>(fc1_w, fc1wT, 768, 3072);
  transpose_cast<<<dim3(24, 96), tb, 0, stream>>>(fc2_w, fc2wT, 3072, 768);
  weff_build<<<192, 256, 0, stream>>>(lin_w, weffT);

  ln_rows<<<2048, 256, 0, stream>>>(x, ln1_g, ln1_b, h, 8192);
  gemm_bt<0><<<dim3(64, 2), 256, 0, stream>>>(h, wqkvT, nullptr, nullptr, qkv,
                                              8192, 192, 768, 192);
  attn_fwd<<<dim3(256, 4), 128, 0, stream>>>(qkv, pout, pm, pl);
  attn_merge<<<2048, 256, 0, stream>>>(pout, pm, pl, oh);
  gemm_bt<1><<<dim3(64, 6), 256, 0, stream>>>(oh, weffT, lin_b, x, out1,
                                              8192, 768, 64, 768);
  ln_rows<<<2048, 256, 0, stream>>>(out1, ln1_g, ln1_b, h, 8192);
  // FC1: [8192,768] @ [768,3072] -> gelu -> a1 (8-phase 256^2)
  gemm8p<2><<<dim3(32, 12), 512, 0, stream>>>(h, fc1wT, fc1_b, a1,
                                              8192, 3072, 768, 768, 3072);
  // FC2: [8192,3072] @ [3072,768], 2-way split-K, bf16 partials
  gemm8p<4><<<dim3(32, 3, 2), 512, 0, stream>>>(a1, fc2wT, nullptr, fc2p,
                                                8192, 768, 3072, 1536, 768);
  fc2_reduce<<<3072, 256, 0, stream>>>(fc2p, fc2_b, out1, out);
}

// Round 5
// 349.878 us; speedup vs baseline: 1.0147x; 1.0147x over previous
//
#include <hip/hip_runtime.h>

typedef unsigned short u16;
typedef unsigned int u32;
typedef __bf16 bf16x8 __attribute__((ext_vector_type(8)));
typedef float f32x4 __attribute__((ext_vector_type(4)));
typedef u16 ushortx8 __attribute__((ext_vector_type(8)));

__device__ __forceinline__ u16 f2bf(float f) {
  u32 u = __float_as_uint(f);
  u32 r = (u + 0x7FFFu + ((u >> 16) & 1u)) >> 16;
  return (u16)r;
}
__device__ __forceinline__ float bf2f(u16 v) {
  return __uint_as_float((u32)v << 16);
}

__device__ __forceinline__ float gelu_exact(float x) {
  return 0.5f * x * (1.f + erff(x * 0.70710678118654752f));
}

// async global->LDS, 16B per lane. LDS dest is wave-uniform base + lane*16.
__device__ __forceinline__ void gload16(const u16* g, u16* l) {
  __builtin_amdgcn_global_load_lds((const __attribute__((address_space(1))) void*)g,
                                   (__attribute__((address_space(3))) void*)l, 16, 0, 0);
}

// ---------------- transpose + cast fp32 [R,C] -> bf16 [C,R] ----------------
__global__ void transpose_cast(const float* __restrict__ in, u16* __restrict__ out,
                               int R, int C) {
  __shared__ float tile[32][33];
  int c0 = blockIdx.x * 32, r0 = blockIdx.y * 32;
  int tx = threadIdx.x, ty = threadIdx.y;  // 32 x 8
  for (int i = 0; i < 32; i += 8) {
    int r = r0 + ty + i, c = c0 + tx;
    tile[ty + i][tx] = (r < R && c < C) ? in[(long)r * C + c] : 0.f;
  }
  __syncthreads();
  for (int i = 0; i < 32; i += 8) {
    int oc = c0 + ty + i, orr = r0 + tx;
    if (oc < C && orr < R) out[(long)oc * R + orr] = f2bf(tile[tx][ty + i]);
  }
}

// ------- W_eff^T[n,d] = sum_j lin_w[j*64+d, n]  (tile-of-12 folded GEMM) -------
__global__ void weff_build(const float* __restrict__ lin_w, u16* __restrict__ weffT) {
  int idx = blockIdx.x * 256 + threadIdx.x;
  if (idx >= 768 * 64) return;
  int n = idx % 768, d = idx / 768;
  float s = 0.f;
#pragma unroll
  for (int j = 0; j < 12; j++) s += lin_w[(long)(j * 64 + d) * 768 + n];
  weffT[(long)n * 64 + d] = f2bf(s);
}

// ---------------- LayerNorm: one wave per 768-row, bf16 out ----------------
__global__ __launch_bounds__(256)
void ln_rows(const float* __restrict__ in, const float* __restrict__ gamma,
             const float* __restrict__ beta, u16* __restrict__ out, int nrows) {
  int gid = blockIdx.x * blockDim.x + threadIdx.x;
  int wid = gid >> 6, l = gid & 63;
  if (wid >= nrows) return;
  const float4* row = (const float4*)(in + (long)wid * 768);
  float4 v[3];
  float s = 0.f, s2 = 0.f;
#pragma unroll
  for (int j = 0; j < 3; j++) {
    v[j] = row[l + 64 * j];
    s += v[j].x + v[j].y + v[j].z + v[j].w;
    s2 += v[j].x * v[j].x + v[j].y * v[j].y + v[j].z * v[j].z + v[j].w * v[j].w;
  }
#pragma unroll
  for (int off = 1; off < 64; off <<= 1) {
    s += __shfl_xor(s, off);
    s2 += __shfl_xor(s2, off);
  }
  float mean = s * (1.f / 768.f);
  float rstd = rsqrtf(s2 * (1.f / 768.f) - mean * mean + 1e-5f);
  u16* orow = out + (long)wid * 768;
#pragma unroll
  for (int j = 0; j < 3; j++) {
    float4 g = ((const float4*)gamma)[l + 64 * j];
    float4 b = ((const float4*)beta)[l + 64 * j];
    ushort4 o;
    o.x = f2bf((v[j].x - mean) * rstd * g.x + b.x);
    o.y = f2bf((v[j].y - mean) * rstd * g.y + b.y);
    o.z = f2bf((v[j].z - mean) * rstd * g.z + b.z);
    o.w = f2bf((v[j].w - mean) * rstd * g.w + b.w);
    ((ushort4*)orow)[l + 64 * j] = o;
  }
}

// ------------- generic bf16 GEMM (128x128, BK=32, m97-style) for small GEMMs -------------
// EPI 0: bf16 out, no bias.  EPI 1: f32 out = acc + bias + res.
template <int EPI>
__global__ __launch_bounds__(256, 2)
void gemm_bt(const u16* __restrict__ A, const u16* __restrict__ Bt,
             const float* __restrict__ bias, const float* __restrict__ res,
             void* __restrict__ outv, int M, int N, int K, int ldo) {
  __shared__ __align__(16) u16 Alds[128 * 32];
  __shared__ __align__(16) u16 Blds[128 * 32];
  const int t = threadIdx.x;
  const int w = t >> 6, l = t & 63;
  const int wr = w >> 1, wc = w & 1;
  const int srow = w * 32 + (l >> 2);
  const int scol = (l & 3) * 8;
  const u16* aptr = A + (long)(blockIdx.x * 128 + srow) * K + scol;
  const u16* bptr = Bt + (long)(blockIdx.y * 128 + srow) * K + scol;
  const long j16 = (long)16 * K;
  u16* albase = &Alds[(w * 32) * 32];
  u16* blbase = &Blds[(w * 32) * 32];
  const int ar = (wr * 64 + (l & 15)) * 32 + (l >> 4) * 8;
  const int br = (wc * 64 + (l & 15)) * 32 + (l >> 4) * 8;
  f32x4 acc[4][4] = {};
  for (int ks = 0; ks < K; ks += 32) {
    __syncthreads();
    gload16(aptr, albase);
    gload16(aptr + j16, albase + 16 * 32);
    gload16(bptr, blbase);
    gload16(bptr + j16, blbase + 16 * 32);
    asm volatile("s_waitcnt vmcnt(0)" ::: "memory");
    __syncthreads();
    bf16x8 af[4], bfr[4];
#pragma unroll
    for (int i = 0; i < 4; i++) af[i] = *(const bf16x8*)(&Alds[ar + i * 16 * 32]);
#pragma unroll
    for (int i = 0; i < 4; i++) bfr[i] = *(const bf16x8*)(&Blds[br + i * 16 * 32]);
#pragma unroll
    for (int mf = 0; mf < 4; mf++)
#pragma unroll
      for (int nf = 0; nf < 4; nf++)
        acc[mf][nf] = __builtin_amdgcn_mfma_f32_16x16x32_bf16(af[mf], bfr[nf], acc[mf][nf], 0, 0, 0);
    aptr += 32;
    bptr += 32;
  }
  const int rowbase = blockIdx.x * 128 + wr * 64 + ((l >> 4) * 4);
  const int colbase = blockIdx.y * 128 + wc * 64 + (l & 15);
#pragma unroll
  for (int nf = 0; nf < 4; nf++) {
    int col = colbase + nf * 16;
    if (col >= N) continue;
    float bv = (EPI == 0) ? 0.f : bias[col];
#pragma unroll
    for (int mf = 0; mf < 4; mf++) {
#pragma unroll
      for (int i = 0; i < 4; i++) {
        long row = rowbase + mf * 16 + i;
        float v = acc[mf][nf][i] + bv;
        if (EPI == 1) {
          v += res[row * ldo + col];
          ((float*)outv)[row * ldo + col] = v;
        } else {
          ((u16*)outv)[row * ldo + col] = f2bf(v);
        }
      }
    }
  }
}

// ================= 256x256 8-phase GEMM (m201 template, race-fixed, unpinned) =================
// BK=64, 2-dbuf 128KiB LDS, 8 waves (2Mx4N), wave tile 128x64.
// Half-tile stage order per K-tile: h0=B-half0, h1=A-half0, h2=A-half1, h3=B-half1.
// Stage lead 6: tile T's phases stage {T+1h2, T+1h3, T+2h0, T+2h1}.
//   Current-buffer stages: B-half at P3 (B consumed end-P2), A-half at P4 (A consumed end-P3).
// Reads: A @ {P1,P3}, B @ {P1,P2}. Boundary waits: vmcnt(4) steady, vmcnt(0) into last 2 tiles.
// Phase = {ds_reads+STAGE; s_barrier; lgkmcnt(0)+sched_barrier(0) [rule #18 + drain-before-
// barrier2 invariant]; setprio MFMA; s_barrier}. NO other sched_barriers (m141 lesson).
// EPI 2: bf16 gelu(acc+bias).  EPI 4: bf16 raw partial at outv + z*M*ldo.
template <int EPI>
__global__ __launch_bounds__(512, 2)
void gemm8p(const u16* __restrict__ A, const u16* __restrict__ Bt,
            const float* __restrict__ bias, u16* __restrict__ outv,
            int M, int N, int lda, int Ks, int ldo) {
  __shared__ __align__(16) u16 lds[2][2][16384];  // [dbuf][A=0/B=1][half*8192 + r*64 + c]
  const int t = threadIdx.x;
  const int w = t >> 6, l = t & 63;
  const int wm = w >> 2, wn = w & 3;
  const int NT = Ks >> 6;
  const long kb = (long)blockIdx.z * Ks;
  const u16* Ag = A + (long)blockIdx.x * 256 * lda + kb;
  const u16* Bg = Bt + (long)blockIdx.y * 256 * lda + kb;
  // staging: chunk c (16B) sits at linear LDS chunk c = row*8 + slot; holds logical
  // k-chunk = slot ^ (row&7). Inverse-swizzled global source per lane (rule #21).
  const int c0 = t, c1 = t + 512;
  const int r0 = c0 >> 3, r1 = c1 >> 3;
  const int co0 = ((c0 & 7) ^ (r0 & 7)) << 3;
  const int co1 = ((c1 & 7) ^ (r1 & 7)) << 3;
  const int db0 = w * 512;         // u16 offset of wave's chunk base, issue 0
  const int db1 = 4096 + w * 512;  // issue 1
  // swizzled ds_read offsets: slot = (l>>4 [+4 for ks=1]) ^ (row&7), row&7 == l&7
  const int arb = (wm * 128 + (l & 15)) * 64;
  const int brb = (wn * 64 + (l & 15)) * 64;
  const int ck0 = (((l >> 4) + 0) ^ (l & 7)) << 3;
  const int ck1 = (((l >> 4) + 4) ^ (l & 7)) << 3;

  f32x4 acc[8][4] = {};
  bf16x8 a[4][2], b0[2][2], b1[2][2];

  auto STAGE = [&](int s) {
    if (s >= 4 * NT) return;
    int T = s >> 2, h = s & 3;
    int isB = (h == 0 || h == 3);    // h0,h3 = B halves; h1,h2 = A halves
    int half = h >> 1;               // h0->B0, h1->A0, h2->A1, h3->B1
    u16* base = &lds[T & 1][isB][half * 8192];
    const u16* src = (isB ? Bg : Ag) + (long)(half * 128) * lda + T * 64;
    gload16(src + (long)r0 * lda + co0, base + db0);
    gload16(src + (long)r1 * lda + co1, base + db1);
  };
  auto LDA_ = [&](int buf, int qm) {
#pragma unroll
    for (int i = 0; i < 4; i++) {
      const u16* base = &lds[buf][0][arb + (qm * 4 + i) * 1024];
      a[i][0] = *(const bf16x8*)(base + ck0);
      a[i][1] = *(const bf16x8*)(base + ck1);
    }
  };
  auto LDB_ = [&](int buf, int qn, bf16x8 (&bb)[2][2]) {
#pragma unroll
    for (int j = 0; j < 2; j++) {
      const u16* base = &lds[buf][1][brb + (qn * 2 + j) * 1024];
      bb[j][0] = *(const bf16x8*)(base + ck0);
      bb[j][1] = *(const bf16x8*)(base + ck1);
    }
  };
  auto MM = [&](int qm, int qn, bf16x8 (&bb)[2][2]) {
    __builtin_amdgcn_s_setprio(1);
#pragma unroll
    for (int i = 0; i < 4; i++)
#pragma unroll
      for (int j = 0; j < 2; j++)
#pragma unroll
        for (int ks = 0; ks < 2; ks++)
          acc[qm * 4 + i][qn * 2 + j] = __builtin_amdgcn_mfma_f32_16x16x32_bf16(
              a[i][ks], bb[j][ks], acc[qm * 4 + i][qn * 2 + j], 0, 0, 0);
    __builtin_amdgcn_s_setprio(0);
  };
  auto BAR = [&]() { __builtin_amdgcn_s_barrier(); };
  auto DRAIN = [&]() {
    asm volatile("s_waitcnt lgkmcnt(0)" ::: "memory");
    __builtin_amdgcn_sched_barrier(0);  // rule #18: keep MFMA after the drain
  };

  // prologue: T0 fully (h0..h3) + T1 h0,h1 in flight = 12 loads
  for (int i = 0; i < 6; i++) STAGE(i);
  asm volatile("s_waitcnt vmcnt(4)" ::: "memory");  // T0's 8 landed
  BAR();
  for (int T = 0; T < NT; T++) {
    const int buf = T & 1;
    // P1
    LDA_(buf, 0); LDB_(buf, 0, b0); STAGE(4 * T + 6);
    BAR(); DRAIN();
    MM(0, 0, b0);
    BAR();
    // P2
    LDB_(buf, 1, b1); STAGE(4 * T + 7);
    BAR(); DRAIN();
    MM(0, 1, b1);
    BAR();
    // P3
    LDA_(buf, 1); STAGE(4 * T + 8);
    BAR(); DRAIN();
    MM(1, 1, b1);
    BAR();
    // P4 + tile boundary wait
    STAGE(4 * T + 9);
    if (T < NT - 2) { asm volatile("s_waitcnt vmcnt(4)" ::: "memory"); }
    else            { asm volatile("s_waitcnt vmcnt(0)" ::: "memory"); }
    BAR(); DRAIN();
    MM(1, 0, b0);
    BAR();
  }

  const int rowb = blockIdx.x * 256 + wm * 128 + ((l >> 4) * 4);
  const int colb = blockIdx.y * 256 + wn * 64 + (l & 15);
  u16* op = outv + (EPI == 4 ? (size_t)blockIdx.z * M * ldo : (size_t)0);
#pragma unroll
  for (int nf = 0; nf < 4; nf++) {
    int col = colb + nf * 16;
    float bv = (EPI == 2) ? bias[col] : 0.f;
#pragma unroll
    for (int mf = 0; mf < 8; mf++) {
#pragma unroll
      for (int i = 0; i < 4; i++) {
        long row = rowb + mf * 16 + i;
        float v = acc[mf][nf][i] + bv;
        if (EPI == 2) v = gelu_exact(v);
        op[row * ldo + col] = f2bf(v);
      }
    }
  }
}

// out = p0 + p1 + bias + res  (FC2 split-K reduce, f32 out)
__global__ __launch_bounds__(256)
void fc2_reduce(const u16* __restrict__ p, const float* __restrict__ bias,
                const float* __restrict__ res, float* __restrict__ out) {
  size_t base = ((size_t)blockIdx.x * 256 + threadIdx.x) * 8;
  ushortx8 pa = *(const ushortx8*)(p + base);
  ushortx8 pb = *(const ushortx8*)(p + (size_t)8192 * 768 + base);
  int col = (int)(base % 768);
  float4 r0 = *(const float4*)(res + base);
  float4 r1 = *(const float4*)(res + base + 4);
  float4 g0 = *(const float4*)(bias + col);
  float4 g1 = *(const float4*)(bias + col + 4);
  float4 o0, o1;
  o0.x = bf2f(pa[0]) + bf2f(pb[0]) + r0.x + g0.x;
  o0.y = bf2f(pa[1]) + bf2f(pb[1]) + r0.y + g0.y;
  o0.z = bf2f(pa[2]) + bf2f(pb[2]) + r0.z + g0.z;
  o0.w = bf2f(pa[3]) + bf2f(pb[3]) + r0.w + g0.w;
  o1.x = bf2f(pa[4]) + bf2f(pb[4]) + r1.x + g1.x;
  o1.y = bf2f(pa[5]) + bf2f(pb[5]) + r1.y + g1.y;
  o1.z = bf2f(pa[6]) + bf2f(pb[6]) + r1.z + g1.z;
  o1.w = bf2f(pa[7]) + bf2f(pb[7]) + r1.w + g1.w;
  *(float4*)(out + base) = o0;
  *(float4*)(out + base + 4) = o1;
}

// ---------------- flash attention, 4-way KV split ----------------
__global__ __launch_bounds__(128)
void attn_fwd(const u16* __restrict__ qkv, float* __restrict__ pout,
              float* __restrict__ pm, float* __restrict__ pl) {
  __shared__ __align__(16) u16 Klds[32 * 72];
  __shared__ __align__(16) u16 Vlds[64 * 40];
  __shared__ __align__(16) u16 Plds[2][16 * 40];
  const int t = threadIdx.x, w = t >> 6, l = t & 63;
  const int r0 = blockIdx.x * 32;
  const int sp = blockIdx.y;
  const long bb = (long)(r0 & ~2047);
  const int qrow = r0 + w * 16 + (l & 15);
  bf16x8 qf0 = *(const bf16x8*)(qkv + (long)qrow * 192 + ((l >> 4) * 8));
  bf16x8 qf1 = *(const bf16x8*)(qkv + (long)qrow * 192 + 32 + ((l >> 4) * 8));
  f32x4 po[4] = {};
  float m_i[4], l_i[4];
#pragma unroll
  for (int i = 0; i < 4; i++) { m_i[i] = -1e30f; l_i[i] = 0.f; }
  const int kkey = t >> 3, kseg = t & 7;
  for (int st = sp * 512; st < sp * 512 + 512; st += 32) {
    uint4 k0 = *(const uint4*)(qkv + (bb + st + kkey) * 192 + 64 + kseg * 8);
    uint4 k1 = *(const uint4*)(qkv + (bb + st + 16 + kkey) * 192 + 64 + kseg * 8);
    u16 vv[16];
#pragma unroll
    for (int i = 0; i < 16; i++) {
      int e = t + 128 * i;
      vv[i] = qkv[(bb + st + (e >> 6)) * 192 + 128 + (e & 63)];
    }
    __syncthreads();
    *(uint4*)(&Klds[kkey * 72 + kseg * 8]) = k0;
    *(uint4*)(&Klds[(16 + kkey) * 72 + kseg * 8]) = k1;
#pragma unroll
    for (int i = 0; i < 16; i++) {
      int e = t + 128 * i;
      Vlds[(e & 63) * 40 + (e >> 6)] = vv[i];
    }
    __syncthreads();
    f32x4 s0 = {}, s1 = {};
    {
      bf16x8 ka = *(const bf16x8*)(&Klds[(l & 15) * 72 + ((l >> 4) * 8)]);
      bf16x8 kb = *(const bf16x8*)(&Klds[(l & 15) * 72 + 32 + ((l >> 4) * 8)]);
      s0 = __builtin_amdgcn_mfma_f32_16x16x32_bf16(qf0, ka, s0, 0, 0, 0);
      s0 = __builtin_amdgcn_mfma_f32_16x16x32_bf16(qf1, kb, s0, 0, 0, 0);
      bf16x8 kc = *(const bf16x8*)(&Klds[(16 + (l & 15)) * 72 + ((l >> 4) * 8)]);
      bf16x8 kd = *(const bf16x8*)(&Klds[(16 + (l & 15)) * 72 + 32 + ((l >> 4) * 8)]);
      s1 = __builtin_amdgcn_mfma_f32_16x16x32_bf16(qf0, kc, s1, 0, 0, 0);
      s1 = __builtin_amdgcn_mfma_f32_16x16x32_bf16(qf1, kd, s1, 0, 0, 0);
    }
    float sf[4];
#pragma unroll
    for (int i = 0; i < 4; i++) {
      float a = s0[i] * 0.125f, b = s1[i] * 0.125f;
      float tm = fmaxf(a, b);
#pragma unroll
      for (int off = 1; off < 16; off <<= 1) tm = fmaxf(tm, __shfl_xor(tm, off));
      float mn = fmaxf(m_i[i], tm);
      sf[i] = __expf(m_i[i] - mn);
      m_i[i] = mn;
      a = __expf(a - mn);
      b = __expf(b - mn);
      float rs = a + b;
#pragma unroll
      for (int off = 1; off < 16; off <<= 1) rs += __shfl_xor(rs, off);
      l_i[i] = l_i[i] * sf[i] + rs;
      int prow = (l >> 4) * 4 + i;
      Plds[w][prow * 40 + (l & 15)] = f2bf(a);
      Plds[w][prow * 40 + 16 + (l & 15)] = f2bf(b);
    }
#pragma unroll
    for (int n = 0; n < 4; n++)
#pragma unroll
      for (int i = 0; i < 4; i++) po[n][i] *= sf[i];
    bf16x8 pf = *(const bf16x8*)(&Plds[w][(l & 15) * 40 + ((l >> 4) * 8)]);
#pragma unroll
    for (int n = 0; n < 4; n++) {
      bf16x8 vf = *(const bf16x8*)(&Vlds[(n * 16 + (l & 15)) * 40 + ((l >> 4) * 8)]);
      po[n] = __builtin_amdgcn_mfma_f32_16x16x32_bf16(pf, vf, po[n], 0, 0, 0);
    }
  }
#pragma unroll
  for (int i = 0; i < 4; i++) {
    long row = r0 + w * 16 + ((l >> 4) * 4) + i;
    if ((l & 15) == 0) {
      pm[(long)sp * 8192 + row] = m_i[i];
      pl[(long)sp * 8192 + row] = l_i[i];
    }
#pragma unroll
    for (int n = 0; n < 4; n++)
      pout[((long)sp * 8192 + row) * 64 + n * 16 + (l & 15)] = po[n][i];
  }
}

__global__ __launch_bounds__(256)
void attn_merge(const float* __restrict__ pout, const float* __restrict__ pm,
                const float* __restrict__ pl, u16* __restrict__ oh) {
  int gid = blockIdx.x * 256 + threadIdx.x;
  int row = gid >> 6;
  float M = -1e30f;
#pragma unroll
  for (int s = 0; s < 4; s++) M = fmaxf(M, pm[s * 8192 + row]);
  float L = 0.f, acc = 0.f;
#pragma unroll
  for (int s = 0; s < 4; s++) {
    float e = __expf(pm[s * 8192 + row] - M);
    L += pl[s * 8192 + row] * e;
    acc += pout[((long)s * 8192 + row) * 64 + (gid & 63)] * e;
  }
  oh[gid] = f2bf(acc / L);
}

extern "C" void kernel_launch(void* const* d_in, const int* in_sizes, int n_in,
                              void* d_out, int out_size, void* d_ws, size_t ws_size,
                              hipStream_t stream) {
  const float* x = (const float*)d_in[0];
  const float* wq = (const float*)d_in[1];
  const float* wk = (const float*)d_in[2];
  const float* wv = (const float*)d_in[3];
  const float* lin_w = (const float*)d_in[4];
  const float* lin_b = (const float*)d_in[5];
  const float* ln1_g = (const float*)d_in[6];
  const float* ln1_b = (const float*)d_in[7];
  const float* fc1_w = (const float*)d_in[8];
  const float* fc1_b = (const float*)d_in[9];
  const float* fc2_w = (const float*)d_in[10];
  const float* fc2_b = (const float*)d_in[11];
  float* out = (float*)d_out;

  char* p = (char*)d_ws;
  u16* wqkvT = (u16*)p; p += 256 * 768 * 2;
  u16* weffT = (u16*)p; p += 768 * 64 * 2;
  u16* fc1wT = (u16*)p; p += (size_t)3072 * 768 * 2;
  u16* fc2wT = (u16*)p; p += (size_t)768 * 3072 * 2;
  u16* h = (u16*)p; p += (size_t)8192 * 768 * 2;
  u16* qkv = (u16*)p; p += (size_t)8192 * 192 * 2;
  u16* oh = (u16*)p; p += (size_t)8192 * 64 * 2;
  float* out1 = (float*)p; p += (size_t)8192 * 768 * 4;
  u16* a1 = (u16*)p; p += (size_t)8192 * 3072 * 2;
  u16* fc2p = (u16*)p; p += (size_t)2 * 8192 * 768 * 2;  // FC2 split-K bf16 partials
  // attention partials alias a1 (a1 written only later, by FC1)
  float* pout = (float*)a1;
  float* pm = pout + (size_t)4 * 8192 * 64;
  float* pl = pm + 4 * 8192;

  dim3 tb(32, 8);
  transpose_cast<<<dim3(2, 24), tb, 0, stream>>>(wq, wqkvT, 768, 64);
  transpose_cast<<<dim3(2, 24), tb, 0, stream>>>(wk, wqkvT + 64 * 768, 768, 64);
  transpose_cast<<<dim3(2, 24), tb, 0, stream>>>(wv, wqkvT + 128 * 768, 768, 64);
  hipMemsetAsync(wqkvT + 192 * 768, 0, 64 * 768 * 2, stream);
  transpose_cast<<<dim3(96, 24), tb, 0, stream>>>(fc1_w, fc1wT, 768, 3072);
  transpose_cast<<<dim3(24, 96), tb, 0, stream>>>(fc2_w, fc2wT, 3072, 768);
  weff_build<<<192, 256, 0, stream>>>(lin_w, weffT);

  ln_rows<<<2048, 256, 0, stream>>>(x, ln1_g, ln1_b, h, 8192);
  gemm_bt<0><<<dim3(64, 2), 256, 0, stream>>>(h, wqkvT, nullptr, nullptr, qkv,
                                              8192, 192, 768, 192);
  attn_fwd<<<dim3(256, 4), 128, 0, stream>>>(qkv, pout, pm, pl);
  attn_merge<<<2048, 256, 0, stream>>>(pout, pm, pl, oh);
  gemm_bt<1><<<dim3(64, 6), 256, 0, stream>>>(oh, weffT, lin_b, x, out1,
                                              8192, 768, 64, 768);
  ln_rows<<<2048, 256, 0, stream>>>(out1, ln1_g, ln1_b, h, 8192);
  // FC1: [8192,768] @ [768,3072] -> gelu -> a1 (8-phase 256^2)
  gemm8p<2><<<dim3(32, 12), 512, 0, stream>>>(h, fc1wT, fc1_b, a1,
                                              8192, 3072, 768, 768, 3072);
  // FC2: [8192,3072] @ [3072,768], 2-way split-K, bf16 partials
  gemm8p<4><<<dim3(32, 3, 2), 512, 0, stream>>>(a1, fc2wT, nullptr, fc2p,
                                                8192, 768, 3072, 1536, 768);
  fc2_reduce<<<3072, 256, 0, stream>>>(fc2p, fc2_b, out1, out);
}

// Round 7
// 339.897 us; speedup vs baseline: 1.0445x; 1.0294x over previous
//
#include <hip/hip_runtime.h>

typedef unsigned short u16;
typedef unsigned int u32;
typedef __bf16 bf16x8 __attribute__((ext_vector_type(8)));
typedef float f32x4 __attribute__((ext_vector_type(4)));

__device__ __forceinline__ u16 f2bf(float f) {
  u32 u = __float_as_uint(f);
  u32 r = (u + 0x7FFFu + ((u >> 16) & 1u)) >> 16;
  return (u16)r;
}

__device__ __forceinline__ float gelu_exact(float x) {
  return 0.5f * x * (1.f + erff(x * 0.70710678118654752f));
}

// async global->LDS, 16B per lane. LDS dest is wave-uniform base + lane*16.
__device__ __forceinline__ void gload16(const u16* g, u16* l) {
  __builtin_amdgcn_global_load_lds((const __attribute__((address_space(1))) void*)g,
                                   (__attribute__((address_space(3))) void*)l, 16, 0, 0);
}

// ---------------- transpose + cast fp32 [R,C] -> bf16 [C,R] ----------------
__global__ void transpose_cast(const float* __restrict__ in, u16* __restrict__ out,
                               int R, int C) {
  __shared__ float tile[32][33];
  int c0 = blockIdx.x * 32, r0 = blockIdx.y * 32;
  int tx = threadIdx.x, ty = threadIdx.y;  // 32 x 8
  for (int i = 0; i < 32; i += 8) {
    int r = r0 + ty + i, c = c0 + tx;
    tile[ty + i][tx] = (r < R && c < C) ? in[(long)r * C + c] : 0.f;
  }
  __syncthreads();
  for (int i = 0; i < 32; i += 8) {
    int oc = c0 + ty + i, orr = r0 + tx;
    if (oc < C && orr < R) out[(long)oc * R + orr] = f2bf(tile[tx][ty + i]);
  }
}

// ------- W_eff^T[n,d] = sum_j lin_w[j*64+d, n]  (tile-of-12 folded GEMM) -------
__global__ void weff_build(const float* __restrict__ lin_w, u16* __restrict__ weffT) {
  int idx = blockIdx.x * 256 + threadIdx.x;
  if (idx >= 768 * 64) return;
  int n = idx % 768, d = idx / 768;
  float s = 0.f;
#pragma unroll
  for (int j = 0; j < 12; j++) s += lin_w[(long)(j * 64 + d) * 768 + n];
  weffT[(long)n * 64 + d] = f2bf(s);
}

// ---------------- LayerNorm: one wave per 768-row, bf16 out ----------------
__global__ __launch_bounds__(256)
void ln_rows(const float* __restrict__ in, const float* __restrict__ gamma,
             const float* __restrict__ beta, u16* __restrict__ out, int nrows) {
  int gid = blockIdx.x * blockDim.x + threadIdx.x;
  int wid = gid >> 6, l = gid & 63;
  if (wid >= nrows) return;
  const float4* row = (const float4*)(in + (long)wid * 768);
  float4 v[3];
  float s = 0.f, s2 = 0.f;
#pragma unroll
  for (int j = 0; j < 3; j++) {
    v[j] = row[l + 64 * j];
    s += v[j].x + v[j].y + v[j].z + v[j].w;
    s2 += v[j].x * v[j].x + v[j].y * v[j].y + v[j].z * v[j].z + v[j].w * v[j].w;
  }
#pragma unroll
  for (int off = 1; off < 64; off <<= 1) {
    s += __shfl_xor(s, off);
    s2 += __shfl_xor(s2, off);
  }
  float mean = s * (1.f / 768.f);
  float rstd = rsqrtf(s2 * (1.f / 768.f) - mean * mean + 1e-5f);
  u16* orow = out + (long)wid * 768;
#pragma unroll
  for (int j = 0; j < 3; j++) {
    float4 g = ((const float4*)gamma)[l + 64 * j];
    float4 b = ((const float4*)beta)[l + 64 * j];
    ushort4 o;
    o.x = f2bf((v[j].x - mean) * rstd * g.x + b.x);
    o.y = f2bf((v[j].y - mean) * rstd * g.y + b.y);
    o.z = f2bf((v[j].z - mean) * rstd * g.z + b.z);
    o.w = f2bf((v[j].w - mean) * rstd * g.w + b.w);
    ((ushort4*)orow)[l + 64 * j] = o;
  }
}

// ------- generic bf16 GEMM (128x128, BK=32), 2-phase double-buffered staging -------
// T3-minimum recipe: STAGE(next) issued BEFORE ds_read+MFMA(current); one
// drain+barrier per K-step (__syncthreads implies vmcnt(0) lgkmcnt(0)).
// EPI 0: bf16 out, no bias.  EPI 1: f32 out = acc+bias+res.  EPI 2: bf16 gelu(acc+bias).
template <int EPI>
__global__ __launch_bounds__(256, 2)
void gemm_bt(const u16* __restrict__ A, const u16* __restrict__ Bt,
             const float* __restrict__ bias, const float* __restrict__ res,
             void* __restrict__ outv, int M, int N, int K, int ldo) {
  __shared__ __align__(16) u16 Alds[2][128 * 32];
  __shared__ __align__(16) u16 Blds[2][128 * 32];
  const int t = threadIdx.x;
  const int w = t >> 6, l = t & 63;
  const int wr = w >> 1, wc = w & 1;
  // staging: wave w covers rows [w*32, w*32+32) in two 16-row issues.
  const int srow = w * 32 + (l >> 2);
  const int scol = (l & 3) * 8;
  const u16* aptr = A + (long)(blockIdx.x * 128 + srow) * K + scol;
  const u16* bptr = Bt + (long)(blockIdx.y * 128 + srow) * K + scol;
  const long j16 = (long)16 * K;
  const int lw = (w * 32) * 32;  // wave-uniform LDS dest offset (elements)
  const int ar = (wr * 64 + (l & 15)) * 32 + (l >> 4) * 8;
  const int br = (wc * 64 + (l & 15)) * 32 + (l >> 4) * 8;
  f32x4 acc[4][4] = {};
  const int ksteps = K >> 5;
  // prologue: stage K-step 0 into buf 0
  gload16(aptr, &Alds[0][lw]);
  gload16(aptr + j16, &Alds[0][lw + 16 * 32]);
  gload16(bptr, &Blds[0][lw]);
  gload16(bptr + j16, &Blds[0][lw + 16 * 32]);
  aptr += 32;
  bptr += 32;
  __syncthreads();  // drains vmcnt(0): buf0 ready
  for (int ks = 0; ks < ksteps; ks++) {
    const int cur = ks & 1;
    if (ks + 1 < ksteps) {
      const int nxt = cur ^ 1;
      gload16(aptr, &Alds[nxt][lw]);
      gload16(aptr + j16, &Alds[nxt][lw + 16 * 32]);
      gload16(bptr, &Blds[nxt][lw]);
      gload16(bptr + j16, &Blds[nxt][lw + 16 * 32]);
      aptr += 32;
      bptr += 32;
    }
    bf16x8 af[4], bfr[4];
#pragma unroll
    for (int i = 0; i < 4; i++) af[i] = *(const bf16x8*)(&Alds[cur][ar + i * 16 * 32]);
#pragma unroll
    for (int i = 0; i < 4; i++) bfr[i] = *(const bf16x8*)(&Blds[cur][br + i * 16 * 32]);
#pragma unroll
    for (int mf = 0; mf < 4; mf++)
#pragma unroll
      for (int nf = 0; nf < 4; nf++)
        acc[mf][nf] = __builtin_amdgcn_mfma_f32_16x16x32_bf16(af[mf], bfr[nf], acc[mf][nf], 0, 0, 0);
    __syncthreads();  // drains vmcnt(0): next buf staged; all reads of cur done
  }
  const int rowbase = blockIdx.x * 128 + wr * 64 + ((l >> 4) * 4);
  const int colbase = blockIdx.y * 128 + wc * 64 + (l & 15);
#pragma unroll
  for (int nf = 0; nf < 4; nf++) {
    int col = colbase + nf * 16;
    if (col >= N) continue;
    float bv = (EPI == 0) ? 0.f : bias[col];
#pragma unroll
    for (int mf = 0; mf < 4; mf++) {
#pragma unroll
      for (int i = 0; i < 4; i++) {
        long row = rowbase + mf * 16 + i;
        float v = acc[mf][nf][i] + bv;
        if (EPI == 2) v = gelu_exact(v);
        if (EPI == 1) {
          v += res[row * ldo + col];
          ((float*)outv)[row * ldo + col] = v;
        } else {
          ((u16*)outv)[row * ldo + col] = f2bf(v);
        }
      }
    }
  }
}

// ---------------- flash attention, 8-way KV split ----------------
// qkv [8192,192] bf16. Block = 128 threads (2 waves), 32 Q rows, 256 keys per split.
// Writes unnormalized partial O (f32) + per-row (m, l).
__global__ __launch_bounds__(128)
void attn_fwd(const u16* __restrict__ qkv, float* __restrict__ pout,
              float* __restrict__ pm, float* __restrict__ pl) {
  __shared__ __align__(16) u16 Klds[32 * 72];
  __shared__ __align__(16) u16 Vlds[64 * 40];
  __shared__ __align__(16) u16 Plds[2][16 * 40];
  const int t = threadIdx.x, w = t >> 6, l = t & 63;
  const int r0 = blockIdx.x * 32;
  const int sp = blockIdx.y;  // KV split 0..7
  const long bb = (long)(r0 & ~2047);
  const int qrow = r0 + w * 16 + (l & 15);
  bf16x8 qf0 = *(const bf16x8*)(qkv + (long)qrow * 192 + ((l >> 4) * 8));
  bf16x8 qf1 = *(const bf16x8*)(qkv + (long)qrow * 192 + 32 + ((l >> 4) * 8));
  f32x4 po[4] = {};
  float m_i[4], l_i[4];
#pragma unroll
  for (int i = 0; i < 4; i++) { m_i[i] = -1e30f; l_i[i] = 0.f; }
  const int kkey = t >> 3, kseg = t & 7;
  for (int st = sp * 256; st < sp * 256 + 256; st += 32) {
    uint4 k0 = *(const uint4*)(qkv + (bb + st + kkey) * 192 + 64 + kseg * 8);
    uint4 k1 = *(const uint4*)(qkv + (bb + st + 16 + kkey) * 192 + 64 + kseg * 8);
    u16 vv[16];
#pragma unroll
    for (int i = 0; i < 16; i++) {
      int e = t + 128 * i;
      vv[i] = qkv[(bb + st + (e >> 6)) * 192 + 128 + (e & 63)];
    }
    __syncthreads();
    *(uint4*)(&Klds[kkey * 72 + kseg * 8]) = k0;
    *(uint4*)(&Klds[(16 + kkey) * 72 + kseg * 8]) = k1;
#pragma unroll
    for (int i = 0; i < 16; i++) {
      int e = t + 128 * i;
      Vlds[(e & 63) * 40 + (e >> 6)] = vv[i];
    }
    __syncthreads();
    f32x4 s0 = {}, s1 = {};
    {
      bf16x8 ka = *(const bf16x8*)(&Klds[(l & 15) * 72 + ((l >> 4) * 8)]);
      bf16x8 kb = *(const bf16x8*)(&Klds[(l & 15) * 72 + 32 + ((l >> 4) * 8)]);
      s0 = __builtin_amdgcn_mfma_f32_16x16x32_bf16(qf0, ka, s0, 0, 0, 0);
      s0 = __builtin_amdgcn_mfma_f32_16x16x32_bf16(qf1, kb, s0, 0, 0, 0);
      bf16x8 kc = *(const bf16x8*)(&Klds[(16 + (l & 15)) * 72 + ((l >> 4) * 8)]);
      bf16x8 kd = *(const bf16x8*)(&Klds[(16 + (l & 15)) * 72 + 32 + ((l >> 4) * 8)]);
      s1 = __builtin_amdgcn_mfma_f32_16x16x32_bf16(qf0, kc, s1, 0, 0, 0);
      s1 = __builtin_amdgcn_mfma_f32_16x16x32_bf16(qf1, kd, s1, 0, 0, 0);
    }
    float sf[4];
#pragma unroll
    for (int i = 0; i < 4; i++) {
      float a = s0[i] * 0.125f, b = s1[i] * 0.125f;
      float tm = fmaxf(a, b);
#pragma unroll
      for (int off = 1; off < 16; off <<= 1) tm = fmaxf(tm, __shfl_xor(tm, off));
      float mn = fmaxf(m_i[i], tm);
      sf[i] = __expf(m_i[i] - mn);
      m_i[i] = mn;
      a = __expf(a - mn);
      b = __expf(b - mn);
      float rs = a + b;
#pragma unroll
      for (int off = 1; off < 16; off <<= 1) rs += __shfl_xor(rs, off);
      l_i[i] = l_i[i] * sf[i] + rs;
      int prow = (l >> 4) * 4 + i;
      Plds[w][prow * 40 + (l & 15)] = f2bf(a);
      Plds[w][prow * 40 + 16 + (l & 15)] = f2bf(b);
    }
#pragma unroll
    for (int n = 0; n < 4; n++)
#pragma unroll
      for (int i = 0; i < 4; i++) po[n][i] *= sf[i];
    bf16x8 pf = *(const bf16x8*)(&Plds[w][(l & 15) * 40 + ((l >> 4) * 8)]);
#pragma unroll
    for (int n = 0; n < 4; n++) {
      bf16x8 vf = *(const bf16x8*)(&Vlds[(n * 16 + (l & 15)) * 40 + ((l >> 4) * 8)]);
      po[n] = __builtin_amdgcn_mfma_f32_16x16x32_bf16(pf, vf, po[n], 0, 0, 0);
    }
  }
#pragma unroll
  for (int i = 0; i < 4; i++) {
    long row = r0 + w * 16 + ((l >> 4) * 4) + i;
    if ((l & 15) == 0) {
      pm[(long)sp * 8192 + row] = m_i[i];
      pl[(long)sp * 8192 + row] = l_i[i];
    }
#pragma unroll
    for (int n = 0; n < 4; n++)
      pout[((long)sp * 8192 + row) * 64 + n * 16 + (l & 15)] = po[n][i];
  }
}

// merge 8 KV-split partials -> normalized bf16 head output
__global__ __launch_bounds__(256)
void attn_merge(const float* __restrict__ pout, const float* __restrict__ pm,
                const float* __restrict__ pl, u16* __restrict__ oh) {
  int gid = blockIdx.x * 256 + threadIdx.x;  // row*64 + feat
  int row = gid >> 6;
  float M = -1e30f;
#pragma unroll
  for (int s = 0; s < 8; s++) M = fmaxf(M, pm[s * 8192 + row]);
  float L = 0.f, acc = 0.f;
#pragma unroll
  for (int s = 0; s < 8; s++) {
    float e = __expf(pm[s * 8192 + row] - M);
    L += pl[s * 8192 + row] * e;
    acc += pout[((long)s * 8192 + row) * 64 + (gid & 63)] * e;
  }
  oh[gid] = f2bf(acc / L);
}

extern "C" void kernel_launch(void* const* d_in, const int* in_sizes, int n_in,
                              void* d_out, int out_size, void* d_ws, size_t ws_size,
                              hipStream_t stream) {
  const float* x = (const float*)d_in[0];
  const float* wq = (const float*)d_in[1];
  const float* wk = (const float*)d_in[2];
  const float* wv = (const float*)d_in[3];
  const float* lin_w = (const float*)d_in[4];
  const float* lin_b = (const float*)d_in[5];
  const float* ln1_g = (const float*)d_in[6];
  const float* ln1_b = (const float*)d_in[7];
  const float* fc1_w = (const float*)d_in[8];
  const float* fc1_b = (const float*)d_in[9];
  const float* fc2_w = (const float*)d_in[10];
  const float* fc2_b = (const float*)d_in[11];
  float* out = (float*)d_out;

  char* p = (char*)d_ws;
  u16* wqkvT = (u16*)p; p += 256 * 768 * 2;          // [256(pad from 192), 768]
  u16* weffT = (u16*)p; p += 768 * 64 * 2;           // [768, 64]
  u16* fc1wT = (u16*)p; p += (size_t)3072 * 768 * 2; // [3072, 768]
  u16* fc2wT = (u16*)p; p += (size_t)768 * 3072 * 2; // [768, 3072]
  u16* h = (u16*)p; p += (size_t)8192 * 768 * 2;     // LN out (reused for LN2 out)
  u16* qkv = (u16*)p; p += (size_t)8192 * 192 * 2;   // [rows, q|k|v]
  u16* oh = (u16*)p; p += (size_t)8192 * 64 * 2;     // attention head out
  float* out1 = (float*)p; p += (size_t)8192 * 768 * 4;  // residual-1 output
  u16* a1 = (u16*)p; p += (size_t)8192 * 3072 * 2;   // gelu(fc1) out
  // attention partials alias a1 (a1 written only later, by FC1)
  float* pout = (float*)a1;                           // 8*8192*64 f32 = 16 MB
  float* pm = pout + (size_t)8 * 8192 * 64;
  float* pl = pm + 8 * 8192;

  dim3 tb(32, 8);
  // weight prep (bf16, transposed [N,K])
  transpose_cast<<<dim3(2, 24), tb, 0, stream>>>(wq, wqkvT, 768, 64);
  transpose_cast<<<dim3(2, 24), tb, 0, stream>>>(wk, wqkvT + 64 * 768, 768, 64);
  transpose_cast<<<dim3(2, 24), tb, 0, stream>>>(wv, wqkvT + 128 * 768, 768, 64);
  hipMemsetAsync(wqkvT + 192 * 768, 0, 64 * 768 * 2, stream);  // pad rows 192..255
  transpose_cast<<<dim3(96, 24), tb, 0, stream>>>(fc1_w, fc1wT, 768, 3072);
  transpose_cast<<<dim3(24, 96), tb, 0, stream>>>(fc2_w, fc2wT, 3072, 768);
  weff_build<<<192, 256, 0, stream>>>(lin_w, weffT);

  // pipeline
  ln_rows<<<2048, 256, 0, stream>>>(x, ln1_g, ln1_b, h, 8192);
  gemm_bt<0><<<dim3(64, 2), 256, 0, stream>>>(h, wqkvT, nullptr, nullptr, qkv,
                                              8192, 192, 768, 192);
  attn_fwd<<<dim3(256, 8), 128, 0, stream>>>(qkv, pout, pm, pl);
  attn_merge<<<2048, 256, 0, stream>>>(pout, pm, pl, oh);
  gemm_bt<1><<<dim3(64, 6), 256, 0, stream>>>(oh, weffT, lin_b, x, out1,
                                              8192, 768, 64, 768);
  ln_rows<<<2048, 256, 0, stream>>>(out1, ln1_g, ln1_b, h, 8192);
  gemm_bt<2><<<dim3(64, 24), 256, 0, stream>>>(h, fc1wT, fc1_b, nullptr, a1,
                                               8192, 3072, 768, 3072);
  gemm_bt<1><<<dim3(64, 6), 256, 0, stream>>>(a1, fc2wT, fc2_b, out1, out,
                                              8192, 768, 3072, 768);
}

// Round 8
// 338.660 us; speedup vs baseline: 1.0483x; 1.0037x over previous
//
#include <hip/hip_runtime.h>

typedef unsigned short u16;
typedef unsigned int u32;
typedef __bf16 bf16x8 __attribute__((ext_vector_type(8)));
typedef float f32x4 __attribute__((ext_vector_type(4)));

__device__ __forceinline__ u16 f2bf(float f) {
  u32 u = __float_as_uint(f);
  u32 r = (u + 0x7FFFu + ((u >> 16) & 1u)) >> 16;
  return (u16)r;
}

__device__ __forceinline__ float gelu_exact(float x) {
  return 0.5f * x * (1.f + erff(x * 0.70710678118654752f));
}

// async global->LDS, 16B per lane. LDS dest is wave-uniform base + lane*16.
__device__ __forceinline__ void gload16(const u16* g, u16* l) {
  __builtin_amdgcn_global_load_lds((const __attribute__((address_space(1))) void*)g,
                                   (__attribute__((address_space(3))) void*)l, 16, 0, 0);
}

// ---------------- transpose + cast fp32 [R,C] -> bf16 [C,R] ----------------
__global__ void transpose_cast(const float* __restrict__ in, u16* __restrict__ out,
                               int R, int C) {
  __shared__ float tile[32][33];
  int c0 = blockIdx.x * 32, r0 = blockIdx.y * 32;
  int tx = threadIdx.x, ty = threadIdx.y;  // 32 x 8
  for (int i = 0; i < 32; i += 8) {
    int r = r0 + ty + i, c = c0 + tx;
    tile[ty + i][tx] = (r < R && c < C) ? in[(long)r * C + c] : 0.f;
  }
  __syncthreads();
  for (int i = 0; i < 32; i += 8) {
    int oc = c0 + ty + i, orr = r0 + tx;
    if (oc < C && orr < R) out[(long)oc * R + orr] = f2bf(tile[tx][ty + i]);
  }
}

// ------- W_eff^T[n,d] = sum_j lin_w[j*64+d, n]  (tile-of-12 folded GEMM) -------
__global__ void weff_build(const float* __restrict__ lin_w, u16* __restrict__ weffT) {
  int idx = blockIdx.x * 256 + threadIdx.x;
  if (idx >= 768 * 64) return;
  int n = idx % 768, d = idx / 768;
  float s = 0.f;
#pragma unroll
  for (int j = 0; j < 12; j++) s += lin_w[(long)(j * 64 + d) * 768 + n];
  weffT[(long)n * 64 + d] = f2bf(s);
}

// ---------------- LayerNorm: one wave per 768-row, bf16 out ----------------
__global__ __launch_bounds__(256)
void ln_rows(const float* __restrict__ in, const float* __restrict__ gamma,
             const float* __restrict__ beta, u16* __restrict__ out, int nrows) {
  int gid = blockIdx.x * blockDim.x + threadIdx.x;
  int wid = gid >> 6, l = gid & 63;
  if (wid >= nrows) return;
  const float4* row = (const float4*)(in + (long)wid * 768);
  float4 v[3];
  float s = 0.f, s2 = 0.f;
#pragma unroll
  for (int j = 0; j < 3; j++) {
    v[j] = row[l + 64 * j];
    s += v[j].x + v[j].y + v[j].z + v[j].w;
    s2 += v[j].x * v[j].x + v[j].y * v[j].y + v[j].z * v[j].z + v[j].w * v[j].w;
  }
#pragma unroll
  for (int off = 1; off < 64; off <<= 1) {
    s += __shfl_xor(s, off);
    s2 += __shfl_xor(s2, off);
  }
  float mean = s * (1.f / 768.f);
  float rstd = rsqrtf(s2 * (1.f / 768.f) - mean * mean + 1e-5f);
  u16* orow = out + (long)wid * 768;
#pragma unroll
  for (int j = 0; j < 3; j++) {
    float4 g = ((const float4*)gamma)[l + 64 * j];
    float4 b = ((const float4*)beta)[l + 64 * j];
    ushort4 o;
    o.x = f2bf((v[j].x - mean) * rstd * g.x + b.x);
    o.y = f2bf((v[j].y - mean) * rstd * g.y + b.y);
    o.z = f2bf((v[j].z - mean) * rstd * g.z + b.z);
    o.w = f2bf((v[j].w - mean) * rstd * g.w + b.w);
    ((ushort4*)orow)[l + 64 * j] = o;
  }
}

// ------- generic bf16 GEMM (128x128, BK=32), 3-buffer counted-vmcnt pipeline -------
// T3/T4: iter T stages K-step T+2 (lead 2), reads buf[T%3], waits vmcnt(4)
// (stage T+1 landed; T+2's 4 loads stay in flight) + raw s_barrier. vmcnt never
// drains to 0 in steady state. Hazard: buf[(T+2)%3] last read at iter T-1, whose
// reads drained via lgkmcnt(0) before its MFMA, fenced by iter-(T-1) barrier.
// T2: XOR swizzle phys_slot = logical ^ ((row>>1)&3) — inverse on global source
// col, forward on ds_read (rule #21). Kills the 8-way quarter-wave conflict.
// EPI 0: bf16 out, no bias.  EPI 1: f32 out = acc+bias+res.  EPI 2: bf16 gelu(acc+bias).
template <int EPI>
__global__ __launch_bounds__(256, 3)
void gemm_bt(const u16* __restrict__ A, const u16* __restrict__ Bt,
             const float* __restrict__ bias, const float* __restrict__ res,
             void* __restrict__ outv, int M, int N, int K, int ldo) {
  __shared__ __align__(16) u16 Alds[3][128 * 32];
  __shared__ __align__(16) u16 Blds[3][128 * 32];
  const int t = threadIdx.x;
  const int w = t >> 6, l = t & 63;
  const int wr = w >> 1, wc = w & 1;
  // staging: wave w covers rows [w*32, w*32+32) in two 16-row issues.
  // chunk l -> row w*32+(l>>2), phys slot (l&3); holds logical slot (l&3)^((l>>3)&3).
  const int srow = w * 32 + (l >> 2);
  const int scol = ((l & 3) ^ ((l >> 3) & 3)) * 8;  // inverse-swizzled source col
  const u16* aptr = A + (long)(blockIdx.x * 128 + srow) * K + scol;
  const u16* bptr = Bt + (long)(blockIdx.y * 128 + srow) * K + scol;
  const long j16 = (long)16 * K;
  const int lw = (w * 32) * 32;  // wave-uniform LDS dest offset (elements)
  // swizzled ds_read: key constant across fragments (row += 16 keeps (row>>1)&3)
  const int key = ((l & 15) >> 1) & 3;
  const int ar = (wr * 64 + (l & 15)) * 32 + (((l >> 4) ^ key) * 8);
  const int br = (wc * 64 + (l & 15)) * 32 + (((l >> 4) ^ key) * 8);
  f32x4 acc[4][4] = {};
  const int ksteps = K >> 5;

  auto STAGE = [&](int s, int buf) {
    const u16* ap = aptr + (long)s * 32;
    const u16* bp = bptr + (long)s * 32;
    gload16(ap, &Alds[buf][lw]);
    gload16(ap + j16, &Alds[buf][lw + 16 * 32]);
    gload16(bp, &Blds[buf][lw]);
    gload16(bp + j16, &Blds[buf][lw + 16 * 32]);
  };

  // prologue: stages 0,1 in flight (8 loads/wave); wait stage 0 (vmcnt(4))
  STAGE(0, 0);
  STAGE(1, 1);
  asm volatile("s_waitcnt vmcnt(4)" ::: "memory");
  __builtin_amdgcn_s_barrier();
  for (int ks = 0; ks < ksteps; ks++) {
    const int cur = ks % 3;
    if (ks + 2 < ksteps) STAGE(ks + 2, (ks + 2) % 3);
    bf16x8 af[4], bfr[4];
#pragma unroll
    for (int i = 0; i < 4; i++) af[i] = *(const bf16x8*)(&Alds[cur][ar + i * 16 * 32]);
#pragma unroll
    for (int i = 0; i < 4; i++) bfr[i] = *(const bf16x8*)(&Blds[cur][br + i * 16 * 32]);
    asm volatile("s_waitcnt lgkmcnt(0)" ::: "memory");
    __builtin_amdgcn_sched_barrier(0);  // rule #18: MFMA stays after the drain
#pragma unroll
    for (int mf = 0; mf < 4; mf++)
#pragma unroll
      for (int nf = 0; nf < 4; nf++)
        acc[mf][nf] = __builtin_amdgcn_mfma_f32_16x16x32_bf16(af[mf], bfr[nf], acc[mf][nf], 0, 0, 0);
    if (ks < ksteps - 2) {
      asm volatile("s_waitcnt vmcnt(4)" ::: "memory");  // stage ks+1 landed
      __builtin_amdgcn_s_barrier();
    } else if (ks == ksteps - 2) {
      asm volatile("s_waitcnt vmcnt(0)" ::: "memory");  // final stage landed
      __builtin_amdgcn_s_barrier();
    }
  }
  const int rowbase = blockIdx.x * 128 + wr * 64 + ((l >> 4) * 4);
  const int colbase = blockIdx.y * 128 + wc * 64 + (l & 15);
#pragma unroll
  for (int nf = 0; nf < 4; nf++) {
    int col = colbase + nf * 16;
    if (col >= N) continue;
    float bv = (EPI == 0) ? 0.f : bias[col];
#pragma unroll
    for (int mf = 0; mf < 4; mf++) {
#pragma unroll
      for (int i = 0; i < 4; i++) {
        long row = rowbase + mf * 16 + i;
        float v = acc[mf][nf][i] + bv;
        if (EPI == 2) v = gelu_exact(v);
        if (EPI == 1) {
          v += res[row * ldo + col];
          ((float*)outv)[row * ldo + col] = v;
        } else {
          ((u16*)outv)[row * ldo + col] = f2bf(v);
        }
      }
    }
  }
}

// ---------------- flash attention, 8-way KV split ----------------
// qkv [8192,192] bf16. Block = 128 threads (2 waves), 32 Q rows, 256 keys per split.
// Writes unnormalized partial O (f32) + per-row (m, l).
__global__ __launch_bounds__(128)
void attn_fwd(const u16* __restrict__ qkv, float* __restrict__ pout,
              float* __restrict__ pm, float* __restrict__ pl) {
  __shared__ __align__(16) u16 Klds[32 * 72];
  __shared__ __align__(16) u16 Vlds[64 * 40];
  __shared__ __align__(16) u16 Plds[2][16 * 40];
  const int t = threadIdx.x, w = t >> 6, l = t & 63;
  const int r0 = blockIdx.x * 32;
  const int sp = blockIdx.y;  // KV split 0..7
  const long bb = (long)(r0 & ~2047);
  const int qrow = r0 + w * 16 + (l & 15);
  bf16x8 qf0 = *(const bf16x8*)(qkv + (long)qrow * 192 + ((l >> 4) * 8));
  bf16x8 qf1 = *(const bf16x8*)(qkv + (long)qrow * 192 + 32 + ((l >> 4) * 8));
  f32x4 po[4] = {};
  float m_i[4], l_i[4];
#pragma unroll
  for (int i = 0; i < 4; i++) { m_i[i] = -1e30f; l_i[i] = 0.f; }
  const int kkey = t >> 3, kseg = t & 7;
  for (int st = sp * 256; st < sp * 256 + 256; st += 32) {
    uint4 k0 = *(const uint4*)(qkv + (bb + st + kkey) * 192 + 64 + kseg * 8);
    uint4 k1 = *(const uint4*)(qkv + (bb + st + 16 + kkey) * 192 + 64 + kseg * 8);
    u16 vv[16];
#pragma unroll
    for (int i = 0; i < 16; i++) {
      int e = t + 128 * i;
      vv[i] = qkv[(bb + st + (e >> 6)) * 192 + 128 + (e & 63)];
    }
    __syncthreads();
    *(uint4*)(&Klds[kkey * 72 + kseg * 8]) = k0;
    *(uint4*)(&Klds[(16 + kkey) * 72 + kseg * 8]) = k1;
#pragma unroll
    for (int i = 0; i < 16; i++) {
      int e = t + 128 * i;
      Vlds[(e & 63) * 40 + (e >> 6)] = vv[i];
    }
    __syncthreads();
    f32x4 s0 = {}, s1 = {};
    {
      bf16x8 ka = *(const bf16x8*)(&Klds[(l & 15) * 72 + ((l >> 4) * 8)]);
      bf16x8 kb = *(const bf16x8*)(&Klds[(l & 15) * 72 + 32 + ((l >> 4) * 8)]);
      s0 = __builtin_amdgcn_mfma_f32_16x16x32_bf16(qf0, ka, s0, 0, 0, 0);
      s0 = __builtin_amdgcn_mfma_f32_16x16x32_bf16(qf1, kb, s0, 0, 0, 0);
      bf16x8 kc = *(const bf16x8*)(&Klds[(16 + (l & 15)) * 72 + ((l >> 4) * 8)]);
      bf16x8 kd = *(const bf16x8*)(&Klds[(16 + (l & 15)) * 72 + 32 + ((l >> 4) * 8)]);
      s1 = __builtin_amdgcn_mfma_f32_16x16x32_bf16(qf0, kc, s1, 0, 0, 0);
      s1 = __builtin_amdgcn_mfma_f32_16x16x32_bf16(qf1, kd, s1, 0, 0, 0);
    }
    float sf[4];
#pragma unroll
    for (int i = 0; i < 4; i++) {
      float a = s0[i] * 0.125f, b = s1[i] * 0.125f;
      float tm = fmaxf(a, b);
#pragma unroll
      for (int off = 1; off < 16; off <<= 1) tm = fmaxf(tm, __shfl_xor(tm, off));
      float mn = fmaxf(m_i[i], tm);
      sf[i] = __expf(m_i[i] - mn);
      m_i[i] = mn;
      a = __expf(a - mn);
      b = __expf(b - mn);
      float rs = a + b;
#pragma unroll
      for (int off = 1; off < 16; off <<= 1) rs += __shfl_xor(rs, off);
      l_i[i] = l_i[i] * sf[i] + rs;
      int prow = (l >> 4) * 4 + i;
      Plds[w][prow * 40 + (l & 15)] = f2bf(a);
      Plds[w][prow * 40 + 16 + (l & 15)] = f2bf(b);
    }
#pragma unroll
    for (int n = 0; n < 4; n++)
#pragma unroll
      for (int i = 0; i < 4; i++) po[n][i] *= sf[i];
    bf16x8 pf = *(const bf16x8*)(&Plds[w][(l & 15) * 40 + ((l >> 4) * 8)]);
#pragma unroll
    for (int n = 0; n < 4; n++) {
      bf16x8 vf = *(const bf16x8*)(&Vlds[(n * 16 + (l & 15)) * 40 + ((l >> 4) * 8)]);
      po[n] = __builtin_amdgcn_mfma_f32_16x16x32_bf16(pf, vf, po[n], 0, 0, 0);
    }
  }
#pragma unroll
  for (int i = 0; i < 4; i++) {
    long row = r0 + w * 16 + ((l >> 4) * 4) + i;
    if ((l & 15) == 0) {
      pm[(long)sp * 8192 + row] = m_i[i];
      pl[(long)sp * 8192 + row] = l_i[i];
    }
#pragma unroll
    for (int n = 0; n < 4; n++)
      pout[((long)sp * 8192 + row) * 64 + n * 16 + (l & 15)] = po[n][i];
  }
}

// merge 8 KV-split partials -> normalized bf16 head output
__global__ __launch_bounds__(256)
void attn_merge(const float* __restrict__ pout, const float* __restrict__ pm,
                const float* __restrict__ pl, u16* __restrict__ oh) {
  int gid = blockIdx.x * 256 + threadIdx.x;  // row*64 + feat
  int row = gid >> 6;
  float M = -1e30f;
#pragma unroll
  for (int s = 0; s < 8; s++) M = fmaxf(M, pm[s * 8192 + row]);
  float L = 0.f, acc = 0.f;
#pragma unroll
  for (int s = 0; s < 8; s++) {
    float e = __expf(pm[s * 8192 + row] - M);
    L += pl[s * 8192 + row] * e;
    acc += pout[((long)s * 8192 + row) * 64 + (gid & 63)] * e;
  }
  oh[gid] = f2bf(acc / L);
}

extern "C" void kernel_launch(void* const* d_in, const int* in_sizes, int n_in,
                              void* d_out, int out_size, void* d_ws, size_t ws_size,
                              hipStream_t stream) {
  const float* x = (const float*)d_in[0];
  const float* wq = (const float*)d_in[1];
  const float* wk = (const float*)d_in[2];
  const float* wv = (const float*)d_in[3];
  const float* lin_w = (const float*)d_in[4];
  const float* lin_b = (const float*)d_in[5];
  const float* ln1_g = (const float*)d_in[6];
  const float* ln1_b = (const float*)d_in[7];
  const float* fc1_w = (const float*)d_in[8];
  const float* fc1_b = (const float*)d_in[9];
  const float* fc2_w = (const float*)d_in[10];
  const float* fc2_b = (const float*)d_in[11];
  float* out = (float*)d_out;

  char* p = (char*)d_ws;
  u16* wqkvT = (u16*)p; p += 256 * 768 * 2;          // [256(pad from 192), 768]
  u16* weffT = (u16*)p; p += 768 * 64 * 2;           // [768, 64]
  u16* fc1wT = (u16*)p; p += (size_t)3072 * 768 * 2; // [3072, 768]
  u16* fc2wT = (u16*)p; p += (size_t)768 * 3072 * 2; // [768, 3072]
  u16* h = (u16*)p; p += (size_t)8192 * 768 * 2;     // LN out (reused for LN2 out)
  u16* qkv = (u16*)p; p += (size_t)8192 * 192 * 2;   // [rows, q|k|v]
  u16* oh = (u16*)p; p += (size_t)8192 * 64 * 2;     // attention head out
  float* out1 = (float*)p; p += (size_t)8192 * 768 * 4;  // residual-1 output
  u16* a1 = (u16*)p; p += (size_t)8192 * 3072 * 2;   // gelu(fc1) out
  // attention partials alias a1 (a1 written only later, by FC1)
  float* pout = (float*)a1;                           // 8*8192*64 f32 = 16 MB
  float* pm = pout + (size_t)8 * 8192 * 64;
  float* pl = pm + 8 * 8192;

  dim3 tb(32, 8);
  // weight prep (bf16, transposed [N,K])
  transpose_cast<<<dim3(2, 24), tb, 0, stream>>>(wq, wqkvT, 768, 64);
  transpose_cast<<<dim3(2, 24), tb, 0, stream>>>(wk, wqkvT + 64 * 768, 768, 64);
  transpose_cast<<<dim3(2, 24), tb, 0, stream>>>(wv, wqkvT + 128 * 768, 768, 64);
  hipMemsetAsync(wqkvT + 192 * 768, 0, 64 * 768 * 2, stream);  // pad rows 192..255
  transpose_cast<<<dim3(96, 24), tb, 0, stream>>>(fc1_w, fc1wT, 768, 3072);
  transpose_cast<<<dim3(24, 96), tb, 0, stream>>>(fc2_w, fc2wT, 3072, 768);
  weff_build<<<192, 256, 0, stream>>>(lin_w, weffT);

  // pipeline
  ln_rows<<<2048, 256, 0, stream>>>(x, ln1_g, ln1_b, h, 8192);
  gemm_bt<0><<<dim3(64, 2), 256, 0, stream>>>(h, wqkvT, nullptr, nullptr, qkv,
                                              8192, 192, 768, 192);
  attn_fwd<<<dim3(256, 8), 128, 0, stream>>>(qkv, pout, pm, pl);
  attn_merge<<<2048, 256, 0, stream>>>(pout, pm, pl, oh);
  gemm_bt<1><<<dim3(64, 6), 256, 0, stream>>>(oh, weffT, lin_b, x, out1,
                                              8192, 768, 64, 768);
  ln_rows<<<2048, 256, 0, stream>>>(out1, ln1_g, ln1_b, h, 8192);
  gemm_bt<2><<<dim3(64, 24), 256, 0, stream>>>(h, fc1wT, fc1_b, nullptr, a1,
                                               8192, 3072, 768, 3072);
  gemm_bt<1><<<dim3(64, 6), 256, 0, stream>>>(a1, fc2wT, fc2_b, out1, out,
                                              8192, 768, 3072, 768);
}